// Round 4
// baseline (263840.503 us; speedup 1.0000x reference)
//
#include <hip/hip_runtime.h>

#define T_STEPS 8192
#define F_IN 64
#define R_DIM 2048
#define G_BLK 256
#define ROWS_PER_BLK 8   // R_DIM / G_BLK
#define LR 0.9f
#define FLAG_STRIDE 16   // 16 uints = 64 B per flag -> no shared-line stores

// Padded LDS index for x: +4 floats per 64 -> spreads the stride-256B
// ds_read_b128 fan-out across bank groups (<=4-way conflict instead of 32-way).
__device__ __forceinline__ int xidx(int c) { return c + ((c >> 6) << 2); }

// ---------------- proj = u_in @ Win^T + b  (one-time, written into d_out) ----
__global__ __launch_bounds__(256) void esn_proj_kernel(
    const float* __restrict__ u, const float* __restrict__ Winw,
    const float* __restrict__ Winb, float* __restrict__ proj)
{
    __shared__ float u_s[64 * F_IN];                  // 64 timesteps x 64 features
    const int t0 = blockIdx.x * 64;
    const int r  = blockIdx.y * 256 + threadIdx.x;

    const float4* usrc = (const float4*)(u + (size_t)t0 * F_IN);
    float4* udst = (float4*)u_s;
#pragma unroll
    for (int i = 0; i < 4; ++i)
        udst[threadIdx.x + 256 * i] = usrc[threadIdx.x + 256 * i];
    __syncthreads();

    float w[F_IN];
    const float4* wrow = (const float4*)(Winw + (size_t)r * F_IN);
#pragma unroll
    for (int k = 0; k < F_IN / 4; ++k) {
        float4 v = wrow[k];
        w[4*k] = v.x; w[4*k+1] = v.y; w[4*k+2] = v.z; w[4*k+3] = v.w;
    }
    const float bias = Winb[r];

    for (int tt = 0; tt < 64; ++tt) {
        const float4* ur = (const float4*)(u_s + tt * F_IN);  // wave-uniform: broadcast
        float acc = bias;
#pragma unroll
        for (int k = 0; k < F_IN / 4; ++k) {
            float4 uv = ur[k];
            acc += w[4*k] * uv.x + w[4*k+1] * uv.y + w[4*k+2] * uv.z + w[4*k+3] * uv.w;
        }
        proj[(size_t)(t0 + tt) * R_DIM + r] = acc;   // coalesced per tt
    }
}

// ---------------- device-wide flag barrier (all-report / all-check) ----------
// Each block publishes its own padded epoch flag (parallel stores, no RMW);
// thread i of every block spins on flags[i]. Monotonic epochs -> no reset.
// Residency guaranteed by hipLaunchCooperativeKernel.
__device__ __forceinline__ void gbar(unsigned int* flags, unsigned int t,
                                     int tid, int bid)
{
    __syncthreads();           // block's xbuf/out stores are issued
    __threadfence();           // agent-scope release: make them visible (wb L2)
    if (tid == 0)
        __hip_atomic_store(&flags[bid * FLAG_STRIDE], t,
                           __ATOMIC_RELAXED, __HIP_MEMORY_SCOPE_AGENT);
    // thread tid waits for block tid's arrival (G_BLK == blockDim.x == 256)
    for (;;) {
        unsigned int v = __hip_atomic_load(&flags[tid * FLAG_STRIDE],
                                           __ATOMIC_RELAXED, __HIP_MEMORY_SCOPE_AGENT);
        if (v >= t) break;
        __builtin_amdgcn_s_sleep(1);
    }
    __syncthreads();           // whole block has seen all 256 arrivals
    __threadfence();           // agent-scope acquire: invalidate -> fresh x loads
}

// ---------------- persistent recurrence kernel -------------------------------
// 256 blocks x 256 threads (cooperative). Block owns 8 rows of Wres, pinned in
// VGPRs (64 floats/thread). proj is staged in `out`, overwritten with x_t.
__global__ __launch_bounds__(256) void esn_recur_kernel(
    const float* __restrict__ Wres, float* __restrict__ out,
    float* __restrict__ xbuf, unsigned int* flags)
{
    const int tid   = threadIdx.x;
    const int row_l = tid >> 5;          // 0..7  : local row
    const int seg   = tid & 31;          // 0..31 : 64-col segment of that row
    const int bid   = blockIdx.x;
    const int r     = bid * ROWS_PER_BLK + row_l;

    // W fragment: W[r][seg*64 .. seg*64+63] -> 64 VGPRs
    float w[64];
    const float4* wrow = (const float4*)(Wres + (size_t)r * R_DIM + seg * 64);
#pragma unroll
    for (int k = 0; k < 16; ++k) {
        float4 v = wrow[k];
        w[4*k] = v.x; w[4*k+1] = v.y; w[4*k+2] = v.z; w[4*k+3] = v.w;
    }
    // Pin: opaque asm makes each w[k] non-rematerializable -> stays in a VGPR
    // (without this the compiler re-loads Wres from L2 every step; VGPR_Count
    // was 52 in round 2, impossible for a live 64-float array).
#pragma unroll
    for (int k = 0; k < 64; ++k) asm volatile("" : "+v"(w[k]));

    __shared__ float xs[R_DIM + (R_DIM / 64) * 4];   // 8704 B, padded

    // step 0: x0 = tanh(proj[0]) (no leak, no Wres term)
    float xcur = 0.f;
    if (seg == 0) {
        xcur = tanhf(out[r]);
        xbuf[r] = xcur;        // buffer 0
        out[r]  = xcur;
    }

    for (int t = 1; t < T_STEPS; ++t) {
        // prefetch proj[t][r] BEFORE the barrier (read-only, no coherence hazard)
        float p = 0.f;
        if (seg == 0) p = out[(size_t)t * R_DIM + r];

        gbar(flags, (unsigned int)t, tid, bid);      // x_{t-1} globally visible

        // stage full x_{t-1} (8 KB) into LDS, padded layout
        const float4* xp = (const float4*)(xbuf + ((t - 1) & 1) * R_DIM);
#pragma unroll
        for (int i = 0; i < 2; ++i) {
            int q = tid + 256 * i;
            float4 v = xp[q];
            *(float4*)&xs[xidx(4 * q)] = v;
        }
        __syncthreads();

        // 64 FMAs against register-resident W
        const float* xseg = xs + xidx(seg * 64);
        float acc = 0.f;
#pragma unroll
        for (int k = 0; k < 16; ++k) {
            float4 xv = *(const float4*)(xseg + 4 * k);
            acc += w[4*k] * xv.x + w[4*k+1] * xv.y + w[4*k+2] * xv.z + w[4*k+3] * xv.w;
        }
        // reduce 32 segments -> row dot (masks stay within each 32-lane half)
        acc += __shfl_xor(acc, 16);
        acc += __shfl_xor(acc, 8);
        acc += __shfl_xor(acc, 4);
        acc += __shfl_xor(acc, 2);
        acc += __shfl_xor(acc, 1);

        if (seg == 0) {
            float xi = tanhf(p + acc);
            float xn = (1.f - LR) * xcur + LR * xi;
            xcur = xn;                                  // row state stays in-register
            xbuf[(t & 1) * R_DIM + r] = xn;
            out[(size_t)t * R_DIM + r] = xn;
        }
        // no trailing sync: gbar at top of next iter starts with __syncthreads
    }
}

extern "C" void kernel_launch(void* const* d_in, const int* in_sizes, int n_in,
                              void* d_out, int out_size, void* d_ws, size_t ws_size,
                              hipStream_t stream)
{
    const float* u    = (const float*)d_in[0];   // [8192, 64]
    const float* Winw = (const float*)d_in[1];   // [2048, 64]
    const float* Winb = (const float*)d_in[2];   // [2048]
    const float* Wres = (const float*)d_in[3];   // [2048, 2048]
    float* out = (float*)d_out;                  // [8192, 2048]

    float* xbuf = (float*)d_ws;                                   // 2 x 2048 floats
    unsigned int* flags = (unsigned int*)((char*)d_ws + 2 * R_DIM * sizeof(float));
    const size_t flags_bytes = G_BLK * FLAG_STRIDE * sizeof(unsigned int); // 16 KB

    hipMemsetAsync(flags, 0, flags_bytes, stream);   // capture-legal (ws re-poisoned)

    dim3 pgrid(T_STEPS / 64, R_DIM / 256);
    esn_proj_kernel<<<pgrid, 256, 0, stream>>>(u, Winw, Winb, out);

    // Cooperative launch: co-residency of all 256 blocks guaranteed -> the
    // flag barrier cannot deadlock.
    const float* WresArg = Wres;
    float* outArg  = out;
    float* xbufArg = xbuf;
    unsigned int* flagsArg = flags;
    void* args[] = { (void*)&WresArg, (void*)&outArg, (void*)&xbufArg, (void*)&flagsArg };
    hipLaunchCooperativeKernel((void*)esn_recur_kernel, dim3(G_BLK), dim3(256),
                               args, 0, stream);
}

// Round 6
// 27925.143 us; speedup vs baseline: 9.4481x; 9.4481x over previous
//
#include <hip/hip_runtime.h>

#define T_STEPS 8192
#define F_IN 64
#define R_DIM 2048
#define G_BLK 256
#define ROWS_PER_BLK 8   // R_DIM / G_BLK
#define LR 0.9f
#define FLAG_STRIDE 64   // 64 uints = 256 B per flag -> spread across L3 channels

// Padded LDS index for x: +4 floats per 64 -> keeps 16-B alignment, reduces the
// stride-256B ds_read_b128 fan-out to a 4-way bank conflict (from 32-way).
__device__ __forceinline__ int xidx(int c) { return c + ((c >> 6) << 2); }

// ---------------- proj = u_in @ Win^T + b  (one-time, written into d_out) ----
__global__ __launch_bounds__(256) void esn_proj_kernel(
    const float* __restrict__ u, const float* __restrict__ Winw,
    const float* __restrict__ Winb, float* __restrict__ proj)
{
    __shared__ float u_s[64 * F_IN];                  // 64 timesteps x 64 features
    const int t0 = blockIdx.x * 64;
    const int r  = blockIdx.y * 256 + threadIdx.x;

    const float4* usrc = (const float4*)(u + (size_t)t0 * F_IN);
    float4* udst = (float4*)u_s;
#pragma unroll
    for (int i = 0; i < 4; ++i)
        udst[threadIdx.x + 256 * i] = usrc[threadIdx.x + 256 * i];
    __syncthreads();

    float w[F_IN];
    const float4* wrow = (const float4*)(Winw + (size_t)r * F_IN);
#pragma unroll
    for (int k = 0; k < F_IN / 4; ++k) {
        float4 v = wrow[k];
        w[4*k] = v.x; w[4*k+1] = v.y; w[4*k+2] = v.z; w[4*k+3] = v.w;
    }
    const float bias = Winb[r];

    for (int tt = 0; tt < 64; ++tt) {
        const float4* ur = (const float4*)(u_s + tt * F_IN);  // wave-uniform: broadcast
        float acc = bias;
#pragma unroll
        for (int k = 0; k < F_IN / 4; ++k) {
            float4 uv = ur[k];
            acc += w[4*k] * uv.x + w[4*k+1] * uv.y + w[4*k+2] * uv.z + w[4*k+3] * uv.w;
        }
        proj[(size_t)(t0 + tt) * R_DIM + r] = acc;   // coalesced per tt
    }
}

// ---------------- fence-free device barrier (all-report / all-check) ---------
// NO release/acquire fences (those emit buffer_wbl2/buffer_inv per block per
// step, evicting L2-resident Wres every step — round 2's hidden cost). All
// cross-block data (x, flags) moves via relaxed AGENT-scope atomics, which
// bypass stale caches per-access. Ordering x-stores -> flag-store comes from
// the s_waitcnt vmcnt(0) that __syncthreads() emits (write-through stores:
// completed == visible). Residency guaranteed by hipLaunchCooperativeKernel.
__device__ __forceinline__ void gbar(unsigned int* flags, unsigned int t,
                                     int tid, int bid)
{
    __syncthreads();   // emits s_waitcnt vmcnt(0) + s_barrier: all waves' x
                       // atomic stores are complete (= globally visible)
    if (tid == 0)
        __hip_atomic_store(&flags[bid * FLAG_STRIDE], t,
                           __ATOMIC_RELAXED, __HIP_MEMORY_SCOPE_AGENT);
    // thread tid waits for block tid's arrival (G_BLK == blockDim.x == 256)
    for (;;) {
        unsigned int v = __hip_atomic_load(&flags[tid * FLAG_STRIDE],
                                           __ATOMIC_RELAXED, __HIP_MEMORY_SCOPE_AGENT);
        if (v >= t) break;
        __builtin_amdgcn_s_sleep(1);
    }
    __syncthreads();   // whole block has seen all 256 arrivals; also a
                       // compiler memory barrier (no hoisting of x loads)
}

// ---------------- persistent recurrence kernel -------------------------------
// 256 blocks x 256 threads (cooperative). Block owns 8 rows of Wres, pinned in
// VGPRs (64 floats/thread). proj is staged in `out`, overwritten with x_t.
__global__ __launch_bounds__(256, 1) void esn_recur_kernel(
    const float* __restrict__ Wres, float* __restrict__ out,
    float* __restrict__ xbuf, unsigned int* flags)
{
    const int tid   = threadIdx.x;
    const int row_l = tid >> 5;          // 0..7  : local row
    const int seg   = tid & 31;          // 0..31 : 64-col segment of that row
    const int bid   = blockIdx.x;
    const int r     = bid * ROWS_PER_BLK + row_l;

    // W fragment: W[r][seg*64 .. seg*64+63] -> 64 VGPRs
    float w[64];
    const float4* wrow = (const float4*)(Wres + (size_t)r * R_DIM + seg * 64);
#pragma unroll
    for (int k = 0; k < 16; ++k) {
        float4 v = wrow[k];
        w[4*k] = v.x; w[4*k+1] = v.y; w[4*k+2] = v.z; w[4*k+3] = v.w;
    }
    // Pin each w[k] in a VGPR via opaque asm. MUST be fully unrolled: round 4
    // left this loop rolled -> runtime index -> whole array spilled to scratch
    // (VGPR_Count 52, FETCH_SIZE 3.4x, 3x slower). Unrolled, every w[k] is an
    // asm-defined register value: non-rematerializable, never reloaded.
#pragma unroll
    for (int k = 0; k < 64; ++k) asm volatile("" : "+v"(w[k]));

    __shared__ float xs[R_DIM + (R_DIM / 64) * 4];   // 8704 B, padded

    // step 0: x0 = tanh(proj[0]) (no leak, no Wres term)
    float xcur = 0.f;
    if (seg == 0) {
        xcur = tanhf(out[r]);
        __hip_atomic_store(&xbuf[r], xcur, __ATOMIC_RELAXED,
                           __HIP_MEMORY_SCOPE_AGENT);   // buffer 0
        out[r] = xcur;
    }

    for (int t = 1; t < T_STEPS; ++t) {
        // prefetch proj[t][r] BEFORE the barrier (this thread's own row: only
        // ever written by this thread after proj kernel ended -> normal load)
        float p = 0.f;
        if (seg == 0) p = out[(size_t)t * R_DIM + r];

        gbar(flags, (unsigned int)t, tid, bid);      // all x_{t-1} stores visible

        // gather full x_{t-1} (8 KB) into LDS: 4 x 8-B agent-scope atomic
        // loads per thread (bypass stale L1/L2), then padded LDS writes.
        const unsigned long long* xsrc =
            (const unsigned long long*)(xbuf + ((t - 1) & 1) * R_DIM);
#pragma unroll
        for (int i = 0; i < 4; ++i) {
            int word = tid + 256 * i;                 // 8-B word index, coalesced
            unsigned long long v = __hip_atomic_load(&xsrc[word],
                __ATOMIC_RELAXED, __HIP_MEMORY_SCOPE_AGENT);
            *(unsigned long long*)&xs[xidx(2 * word)] = v;   // 8-B aligned
        }
        __syncthreads();

        // 64 FMAs against register-resident W
        const float* xseg = xs + xidx(seg * 64);
        float acc = 0.f;
#pragma unroll
        for (int k = 0; k < 16; ++k) {
            float4 xv = *(const float4*)(xseg + 4 * k);
            acc += w[4*k] * xv.x + w[4*k+1] * xv.y + w[4*k+2] * xv.z + w[4*k+3] * xv.w;
        }
        // reduce 32 segments -> row dot (masks stay within each 32-lane half)
        acc += __shfl_xor(acc, 16);
        acc += __shfl_xor(acc, 8);
        acc += __shfl_xor(acc, 4);
        acc += __shfl_xor(acc, 2);
        acc += __shfl_xor(acc, 1);

        if (seg == 0) {
            float xi = tanhf(p + acc);
            float xn = (1.f - LR) * xcur + LR * xi;
            xcur = xn;                                  // row state stays in-register
            __hip_atomic_store(&xbuf[(t & 1) * R_DIM + r], xn,
                               __ATOMIC_RELAXED, __HIP_MEMORY_SCOPE_AGENT);
            out[(size_t)t * R_DIM + r] = xn;            // own row: normal store
        }
        // no trailing sync: gbar at top of next iter starts with __syncthreads
    }
}

extern "C" void kernel_launch(void* const* d_in, const int* in_sizes, int n_in,
                              void* d_out, int out_size, void* d_ws, size_t ws_size,
                              hipStream_t stream)
{
    const float* u    = (const float*)d_in[0];   // [8192, 64]
    const float* Winw = (const float*)d_in[1];   // [2048, 64]
    const float* Winb = (const float*)d_in[2];   // [2048]
    const float* Wres = (const float*)d_in[3];   // [2048, 2048]
    float* out = (float*)d_out;                  // [8192, 2048]

    float* xbuf = (float*)d_ws;                                   // 2 x 2048 floats
    unsigned int* flags = (unsigned int*)((char*)d_ws + 2 * R_DIM * sizeof(float));
    const size_t flags_bytes = G_BLK * FLAG_STRIDE * sizeof(unsigned int); // 64 KB

    hipMemsetAsync(flags, 0, flags_bytes, stream);   // capture-legal (ws re-poisoned)

    dim3 pgrid(T_STEPS / 64, R_DIM / 256);
    esn_proj_kernel<<<pgrid, 256, 0, stream>>>(u, Winw, Winb, out);

    // Cooperative launch: co-residency of all 256 blocks guaranteed -> the
    // flag barrier cannot deadlock.
    const float* WresArg = Wres;
    float* outArg  = out;
    float* xbufArg = xbuf;
    unsigned int* flagsArg = flags;
    void* args[] = { (void*)&WresArg, (void*)&outArg, (void*)&xbufArg, (void*)&flagsArg };
    hipLaunchCooperativeKernel((void*)esn_recur_kernel, dim3(G_BLK), dim3(256),
                               args, 0, stream);
}